// Round 3
// baseline (754.574 us; speedup 1.0000x reference)
//
#include <hip/hip_runtime.h>
#include <cfloat>
#include <math.h>

// Problem constants
constexpr int H_  = 6;
constexpr int C_  = 64;
constexpr int OV_ = 4;
constexpr int G_  = 3;
constexpr int NVQ_ = 6;
constexpr int K_  = 1024;
constexpr int D_  = 8;
constexpr int B_  = 32;
constexpr int W_  = 2400;
constexpr int T_  = 600;          // W/OV
constexpr int NPOS_ = B_ * T_;    // 19200
constexpr int FIX_ = H_ * C_;     // 384
constexpr int GD_ = 512;

// Output layout (floats, concatenated in return order)
constexpr size_t OUT_ZQ   = 0;
constexpr size_t OUT_IDX  = (size_t)B_ * H_ * W_ * C_;             // 29491200
constexpr size_t OUT_LOSS = OUT_IDX + (size_t)B_ * NVQ_ * G_ * T_; // 29836800

// Workspace layout (bytes) — IDENTICAL to the 758 µs baseline layout.
constexpr size_t WS_EN   = 0;                                   // double[18432*8] transposed planes [gi*8+d][k]
constexpr size_t WS_ZD   = WS_EN + (size_t)G_*NVQ_*K_*D_*8;     // double[3*19200*8]
constexpr size_t WS_LOSS = WS_ZD + (size_t)G_*NPOS_*D_*8;       // double[8]
constexpr size_t WS_ZQ   = WS_LOSS + 64;                        // float[3*19200*8]

// ---------------------------------------------------------------------------
// K1: normalize codebooks (fp64) into transposed layout en[(gi*8+d)*1024 + k];
//     also zero the loss accumulator. (identical to baseline)
__global__ __launch_bounds__(256) void k1_norm_cb(const float* __restrict__ cb,
                                                  double* __restrict__ en,
                                                  double* __restrict__ loss) {
    int tid = blockIdx.x * 256 + threadIdx.x;
    if (tid == 0) loss[0] = 0.0;
    if (tid >= G_ * NVQ_ * K_) return;
    int k  = tid & (K_ - 1);
    int gi = tid >> 10;               // 0..17  (g*6+i)
    const float* row = cb + ((size_t)gi * K_ + k) * D_;
    double v[D_];
    double ss = 0.0;
#pragma unroll
    for (int d = 0; d < D_; d++) { v[d] = (double)row[d]; ss += v[d] * v[d]; }
    double n = sqrt(ss);
    if (n < 1e-12) n = 1e-12;
#pragma unroll
    for (int d = 0; d < D_; d++)
        en[((size_t)gi * D_ + d) * K_ + k] = v[d] / n;   // division to mimic ref
}

// ---------------------------------------------------------------------------
// K2: fold (pre_process) + proj_down with fp64 accumulation. (unchanged)
constexpr int PSTR_ = 1548;
constexpr int OVS_  = 388;

__global__ __launch_bounds__(256) void k2_fold_pd(const float* __restrict__ ze,
                                                  const float* __restrict__ pd,
                                                  double* __restrict__ zd) {
    __shared__ __align__(16) float zf[8 * PSTR_];
    int tid  = threadIdx.x;
    int pos0 = blockIdx.x * 8;
#pragma unroll
    for (int it = 0; it < 12; it++) {
        int slot = it * 256 + tid;
        int seg  = slot >> 6;
        int li   = slot & 63;
        int p = seg / 6, h = seg - p * 6;
        int pos = pos0 + p;
        int b = pos / T_, t = pos - b * T_;
        const float4 vv = *(const float4*)(ze + ((size_t)((b * H_ + h) * W_ + 4 * t)) * C_ + li * 4);
        int ov = li >> 4;
        int c0 = (li & 15) * 4;
        int base = p * PSTR_ + ov * OVS_ + h;
        zf[base + (c0 + 0) * 6] = vv.x;
        zf[base + (c0 + 1) * 6] = vv.y;
        zf[base + (c0 + 2) * 6] = vv.z;
        zf[base + (c0 + 3) * 6] = vv.w;
    }
    __syncthreads();
    if (tid < 192) {
        int p = tid / 24;
        int combo = tid - p * 24;
        int g = combo >> 3, d = combo & 7;
        const float* pdp = pd + ((size_t)g * D_ + d) * GD_;
        int lbase = p * PSTR_;
        double acc = 0.0;
        for (int jj = 0; jj < GD_; jj += 4) {
            int gd  = g * GD_ + jj;
            int ov  = gd / FIX_;
            int rem = gd - ov * FIX_;
            float4 zv = *(const float4*)&zf[lbase + ov * OVS_ + rem];
            float4 pv = *(const float4*)&pdp[jj];
            acc = fma((double)pv.x, (double)zv.x, acc);
            acc = fma((double)pv.y, (double)zv.y, acc);
            acc = fma((double)pv.z, (double)zv.z, acc);
            acc = fma((double)pv.w, (double)zv.w, acc);
        }
        zd[((size_t)g * NPOS_ + pos0 + p) * D_ + d] = acc;
    }
}

// ---------------------------------------------------------------------------
// K3: residual VQ. fp32 screening of all 1024 codewords (top-1 + top-2 value)
// with a provable margin test; exact fp64 rescan only when the fp32 gap can't
// certify the winner (rare, wave-uniform branch). Residual kept exact in fp64,
// DISTRIBUTED across lanes (lane l<32 holds (m=l>>3, d=l&7)); every lane keeps
// an fp32 replicated copy for the dot products, refreshed via shuffles each
// stream. 32 KB fp32 LDS codebook converted from the fp64 planes at staging.
// Block: 512 threads (8 waves), one group, 32 positions (4 chains/wave).
// NOTE: plain __launch_bounds__(512) — the (512,4) variant made the allocator
// chase 8 waves/SIMD (64-VGPR budget) and spill ~80 MB of scratch traffic.
__global__ __launch_bounds__(512) void k3_rvq(const double* __restrict__ en64,
                                              const double* __restrict__ zd,
                                              float* __restrict__ zq,
                                              double* __restrict__ loss,
                                              float* __restrict__ out_idx) {
    __shared__ __align__(16) float2 en_s[4 * K_];    // 32 KB: planes dp=0..3 over k, (d=2dp, 2dp+1)
    __shared__ double ls[8];
    int tid  = threadIdx.x;
    int wv   = tid >> 6, lane = tid & 63;
    int g     = blockIdx.x / 600;
    int chunk = blockIdx.x - g * 600;
    int mypos0 = chunk * 32 + wv * 4;
    size_t zdbase = ((size_t)g * NPOS_ + mypos0) * D_;

    const double* en64g = en64 + (size_t)g * NVQ_ * D_ * K_;

    // distributed exact state: lane l<32 holds residual element (m=l>>3, d=l&7)
    double zd0 = 0.0, r64 = 0.0;
    if (lane < 32) { zd0 = zd[zdbase + lane]; r64 = zd0; }
    // fp32 replicated copy for screening
    float r32[4][8];
    {
        float fr = (float)r64;
#pragma unroll
        for (int l = 0; l < 32; l++) r32[l >> 3][l & 7] = __shfl(fr, l);
    }
    double loss_acc = 0.0;

    for (int i = 0; i < NVQ_; i++) {
        __syncthreads();   // all waves done reading en_s from previous stream
        {   // stage fp64 codebook -> fp32 LDS planes (8192 doubles -> 4096 float2)
            const double* src = en64g + (size_t)i * D_ * K_;
#pragma unroll
            for (int it = 0; it < 8; it++) {
                int c  = it * 512 + tid;      // 0..4095
                int dp = c >> 10, k = c & 1023;
                double a = src[(size_t)(2 * dp) * K_ + k];
                double b = src[(size_t)(2 * dp + 1) * K_ + k];
                en_s[dp * K_ + k] = make_float2((float)a, (float)b);
            }
        }
        __syncthreads();

        // fp32 screen: top-1 (value+index) and top-2 value per chain
        float smax[4], s2[4]; int sidx[4];
#pragma unroll
        for (int m = 0; m < 4; m++) { smax[m] = -FLT_MAX; s2[m] = -FLT_MAX; sidx[m] = 0; }
#pragma unroll 4
        for (int j = 0; j < 16; j++) {
            int k = j * 64 + lane;
            float2 c0 = en_s[k];
            float2 c1 = en_s[K_ + k];
            float2 c2 = en_s[2 * K_ + k];
            float2 c3 = en_s[3 * K_ + k];
            float cw[8] = {c0.x, c0.y, c1.x, c1.y, c2.x, c2.y, c3.x, c3.y};
#pragma unroll
            for (int m = 0; m < 4; m++) {
                float s = cw[0] * r32[m][0];
#pragma unroll
                for (int d = 1; d < 8; d++) s = fmaf(cw[d], r32[m][d], s);
                float lo = fminf(s, smax[m]);          // loser of (s, running max)
                s2[m] = fmaxf(s2[m], lo);
                if (s > smax[m]) { smax[m] = s; sidx[m] = k; }   // strict >: first index wins
            }
        }
        // cross-lane reduce (top-2 merge; first-index tie-break on top-1)
#pragma unroll
        for (int off = 32; off >= 1; off >>= 1) {
#pragma unroll
            for (int m = 0; m < 4; m++) {
                float om = __shfl_xor(smax[m], off);
                int   oi = __shfl_xor(sidx[m], off);
                float o2 = __shfl_xor(s2[m], off);
                s2[m] = fmaxf(fmaxf(s2[m], o2), fminf(smax[m], om));
                if (om > smax[m] || (om == smax[m] && oi < sidx[m])) { smax[m] = om; sidx[m] = oi; }
            }
        }
        // certify winner vs fp64; rescan exactly if the fp32 gap can't prove it.
        // |s32 - s64| <= ~10*2^-24*||r||; require gap > 4e-6*||r|| (3x margin):
        // gap^2 > 1.6e-11 * ||r||^2
#pragma unroll
        for (int m = 0; m < 4; m++) {
            float rr = 0.f;
#pragma unroll
            for (int d = 0; d < 8; d++) rr = fmaf(r32[m][d], r32[m][d], rr);
            float gap = smax[m] - s2[m];
            if (!(gap * gap > 1.6e-11f * rr)) {        // rare, wave-uniform
                double rm[8];
#pragma unroll
                for (int d = 0; d < 8; d++) rm[d] = __shfl(r64, m * 8 + d);
                const double* base = en64g + (size_t)i * D_ * K_;
                double bmax = -DBL_MAX; int bidx = 0;
                for (int j = 0; j < 16; j++) {
                    int k = j * 64 + lane;
                    double s = 0.0;
#pragma unroll
                    for (int d = 0; d < 8; d++) s = fma(base[(size_t)d * K_ + k], rm[d], s);
                    if (s > bmax) { bmax = s; bidx = k; }
                }
#pragma unroll
                for (int off = 32; off >= 1; off >>= 1) {
                    double om = __shfl_xor(bmax, off);
                    int    oi = __shfl_xor(bidx, off);
                    if (om > bmax || (om == bmax && oi < bidx)) { bmax = om; bidx = oi; }
                }
                sidx[m] = bidx;
            }
        }
        // exact distributed residual update + loss
        int mycode = lane < 8 ? sidx[0] : lane < 16 ? sidx[1] : lane < 24 ? sidx[2] : sidx[3];
        if (lane < 32) {
            double q = en64g[((size_t)i * D_ + (lane & 7)) * K_ + mycode];
            r64 -= q;
            loss_acc = fma(r64, r64, loss_acc);
        }
        if (lane == 0) {
#pragma unroll
            for (int m = 0; m < 4; m++) {
                int pos = mypos0 + m;
                int b = pos / T_, t = pos - b * T_;
                out_idx[((size_t)(b * NVQ_ + i) * G_ + g) * T_ + t] = (float)sidx[m];
            }
        }
        // refresh fp32 copy
        {
            float fr = (float)r64;
#pragma unroll
            for (int l = 0; l < 32; l++) r32[l >> 3][l & 7] = __shfl(fr, l);
        }
    }
    // zq = zd - r_final (distributed -> already one element per lane)
    if (lane < 32) zq[zdbase + lane] = (float)(zd0 - r64);
    // loss: wave tree-sum (lanes>=32 hold 0), per-block reduce, one fp64 atomic
#pragma unroll
    for (int off = 32; off >= 1; off >>= 1) loss_acc += __shfl_xor(loss_acc, off);
    if (lane == 0) ls[wv] = loss_acc;
    __syncthreads();
    if (tid == 0) {
        double s = 0.0;
#pragma unroll
        for (int w2 = 0; w2 < 8; w2++) s += ls[w2];
        atomicAdd(loss, s);
    }
}

// ---------------------------------------------------------------------------
// K4: proj_up + unfold scatter (fp32). 512 threads / 8 positions per block.
__global__ __launch_bounds__(512) void k4_up(const float* __restrict__ zq,
                                             const float* __restrict__ pu,
                                             const double* __restrict__ loss,
                                             float* __restrict__ out_zq,
                                             float* __restrict__ out_loss) {
    __shared__ __align__(16) float pu_s[G_ * GD_ * 9];   // 54 KB, row stride 9
    int tid = threadIdx.x;
#pragma unroll
    for (int it = 0; it < 3; it++) {
        int row = it * 512 + tid;            // 0..1535
        float4 lo = *(const float4*)(pu + (size_t)row * 8);
        float4 hi = *(const float4*)(pu + (size_t)row * 8 + 4);
        float* dst = &pu_s[row * 9];
        dst[0] = lo.x; dst[1] = lo.y; dst[2] = lo.z; dst[3] = lo.w;
        dst[4] = hi.x; dst[5] = hi.y; dst[6] = hi.z; dst[7] = hi.w;
    }
    if (blockIdx.x == 0 && tid == 0) {
        double l = loss[0] * (1.0 / 460800.0);   // /(B*T*D) per group, /G
        out_loss[0] = (float)l;
        out_loss[1] = (float)l;
    }
    __syncthreads();
    int wv = tid >> 6, lane = tid & 63;
    int pos = blockIdx.x * 8 + wv;
    int b = pos / T_, t = pos - b * T_;
    int ov = lane >> 4, c0 = (lane & 15) * 4;
    int gd_min = ov * FIX_ + c0 * 6;
    int g_lo = gd_min >> 9;
    int g_hi = g_lo < 2 ? g_lo + 1 : 2;
    float za[8], zb[8];
    const float* zqa = zq + ((size_t)g_lo * NPOS_ + pos) * D_;
    const float* zqb = zq + ((size_t)g_hi * NPOS_ + pos) * D_;
#pragma unroll
    for (int d = 0; d < 8; d++) { za[d] = zqa[d]; zb[d] = zqb[d]; }
#pragma unroll
    for (int h = 0; h < H_; h++) {
        float4 o;
        float* op = &o.x;
#pragma unroll
        for (int q = 0; q < 4; q++) {
            int gd = ov * FIX_ + (c0 + q) * 6 + h;
            int g  = gd >> 9;
            int j  = gd & 511;
            const float* pr = &pu_s[(g * GD_ + j) * 9];
            bool hi = (g != g_lo);
            float acc = 0.f;
#pragma unroll
            for (int d = 0; d < 8; d++) {
                float zv = hi ? zb[d] : za[d];
                acc = fmaf(zv, pr[d], acc);
            }
            op[q] = acc;
        }
        *(float4*)(out_zq + ((size_t)((b * H_ + h) * W_ + 4 * t + ov)) * C_ + c0) = o;
    }
}

// ---------------------------------------------------------------------------
extern "C" void kernel_launch(void* const* d_in, const int* in_sizes, int n_in,
                              void* d_out, int out_size, void* d_ws, size_t ws_size,
                              hipStream_t stream) {
    const float* ze = (const float*)d_in[0];
    const float* pd = (const float*)d_in[1];
    const float* pu = (const float*)d_in[2];
    const float* cb = (const float*)d_in[3];
    // d_in[4] = num_streams (==6, compile-time NVQ_)

    float* out = (float*)d_out;
    char*  ws  = (char*)d_ws;
    double* ws_en   = (double*)(ws + WS_EN);
    double* ws_zd   = (double*)(ws + WS_ZD);
    double* ws_loss = (double*)(ws + WS_LOSS);
    float*  ws_zq   = (float*)(ws + WS_ZQ);

    k1_norm_cb<<<(G_ * NVQ_ * K_ + 255) / 256, 256, 0, stream>>>(cb, ws_en, ws_loss);
    k2_fold_pd<<<NPOS_ / 8, 256, 0, stream>>>(ze, pd, ws_zd);
    k3_rvq<<<G_ * (NPOS_ / 32), 512, 0, stream>>>(ws_en, ws_zd, ws_zq, ws_loss, out + OUT_IDX);
    k4_up<<<NPOS_ / 8, 512, 0, stream>>>(ws_zq, pu, ws_loss, out + OUT_ZQ, out + OUT_LOSS);
}

// Round 4
// 727.168 us; speedup vs baseline: 1.0377x; 1.0377x over previous
//
#include <hip/hip_runtime.h>
#include <cfloat>
#include <math.h>

// Problem constants
constexpr int H_  = 6;
constexpr int C_  = 64;
constexpr int OV_ = 4;
constexpr int G_  = 3;
constexpr int NVQ_ = 6;
constexpr int K_  = 1024;
constexpr int D_  = 8;
constexpr int B_  = 32;
constexpr int W_  = 2400;
constexpr int T_  = 600;          // W/OV
constexpr int NPOS_ = B_ * T_;    // 19200
constexpr int FIX_ = H_ * C_;     // 384
constexpr int GD_ = 512;

// Output layout (floats, concatenated in return order)
constexpr size_t OUT_ZQ   = 0;
constexpr size_t OUT_IDX  = (size_t)B_ * H_ * W_ * C_;             // 29491200
constexpr size_t OUT_LOSS = OUT_IDX + (size_t)B_ * NVQ_ * G_ * T_; // 29836800

// Workspace layout (bytes) — IDENTICAL to the 758 µs baseline layout.
constexpr size_t WS_EN   = 0;                                   // double[18432*8] transposed planes [gi*8+d][k]
constexpr size_t WS_ZD   = WS_EN + (size_t)G_*NVQ_*K_*D_*8;     // double[3*19200*8]
constexpr size_t WS_LOSS = WS_ZD + (size_t)G_*NPOS_*D_*8;       // double[8]
constexpr size_t WS_ZQ   = WS_LOSS + 64;                        // float[3*19200*8]

// fp32 codebook scratch lives in the OUTPUT buffer (first 576 KB of the zq
// region): written by k1, read by k3, fully overwritten by k4 afterwards.
// Layout: float2 planes [(g*6+i)*4 + dp][k], dp pairs dims (2dp, 2dp+1).

__device__ __forceinline__ float rfl(float x) {
    return __uint_as_float(__builtin_amdgcn_readfirstlane(__float_as_uint(x)));
}

// ---------------------------------------------------------------------------
// K1: normalize codebooks (fp64) into transposed fp64 planes + fp32 float2
//     planes (scratch in out buffer); zero the loss accumulator.
__global__ __launch_bounds__(256) void k1_norm_cb(const float* __restrict__ cb,
                                                  double* __restrict__ en,
                                                  float2* __restrict__ en32,
                                                  double* __restrict__ loss) {
    int tid = blockIdx.x * 256 + threadIdx.x;
    if (tid == 0) loss[0] = 0.0;
    if (tid >= G_ * NVQ_ * K_) return;
    int k  = tid & (K_ - 1);
    int gi = tid >> 10;               // 0..17  (g*6+i)
    const float* row = cb + ((size_t)gi * K_ + k) * D_;
    double v[D_];
    double ss = 0.0;
#pragma unroll
    for (int d = 0; d < D_; d++) { v[d] = (double)row[d]; ss += v[d] * v[d]; }
    double n = sqrt(ss);
    if (n < 1e-12) n = 1e-12;
    double q[D_];
#pragma unroll
    for (int d = 0; d < D_; d++) {
        q[d] = v[d] / n;              // division to mimic ref
        en[((size_t)gi * D_ + d) * K_ + k] = q[d];
    }
#pragma unroll
    for (int dp = 0; dp < 4; dp++)
        en32[((size_t)gi * 4 + dp) * K_ + k] = make_float2((float)q[2 * dp], (float)q[2 * dp + 1]);
}

// ---------------------------------------------------------------------------
// K2: fold (pre_process) + proj_down, fp64 accumulation in 4 interleaved
// partials (breaks the 512-deep serial dfma chain; fixed final sum order).
constexpr int PSTR_ = 1548;
constexpr int OVS_  = 388;

__global__ __launch_bounds__(256) void k2_fold_pd(const float* __restrict__ ze,
                                                  const float* __restrict__ pd,
                                                  double* __restrict__ zd) {
    __shared__ __align__(16) float zf[8 * PSTR_];
    int tid  = threadIdx.x;
    int pos0 = blockIdx.x * 8;
#pragma unroll
    for (int it = 0; it < 12; it++) {
        int slot = it * 256 + tid;
        int seg  = slot >> 6;
        int li   = slot & 63;
        int p = seg / 6, h = seg - p * 6;
        int pos = pos0 + p;
        int b = pos / T_, t = pos - b * T_;
        const float4 vv = *(const float4*)(ze + ((size_t)((b * H_ + h) * W_ + 4 * t)) * C_ + li * 4);
        int ov = li >> 4;
        int c0 = (li & 15) * 4;
        int base = p * PSTR_ + ov * OVS_ + h;
        zf[base + (c0 + 0) * 6] = vv.x;
        zf[base + (c0 + 1) * 6] = vv.y;
        zf[base + (c0 + 2) * 6] = vv.z;
        zf[base + (c0 + 3) * 6] = vv.w;
    }
    __syncthreads();
    if (tid < 192) {
        int p = tid / 24;
        int combo = tid - p * 24;
        int g = combo >> 3, d = combo & 7;
        const float* pdp = pd + ((size_t)g * D_ + d) * GD_;
        int lbase = p * PSTR_;
        double acc[4] = {0.0, 0.0, 0.0, 0.0};
        for (int jj = 0; jj < GD_; jj += 16) {
#pragma unroll
            for (int u = 0; u < 4; u++) {
                int j4  = jj + u * 4;
                int gd  = g * GD_ + j4;
                int ov  = gd / FIX_;
                int rem = gd - ov * FIX_;
                float4 zv = *(const float4*)&zf[lbase + ov * OVS_ + rem];
                float4 pv = *(const float4*)&pdp[j4];
                acc[u] = fma((double)pv.x, (double)zv.x, acc[u]);
                acc[u] = fma((double)pv.y, (double)zv.y, acc[u]);
                acc[u] = fma((double)pv.z, (double)zv.z, acc[u]);
                acc[u] = fma((double)pv.w, (double)zv.w, acc[u]);
            }
        }
        zd[((size_t)g * NPOS_ + pos0 + p) * D_ + d] = (acc[0] + acc[1]) + (acc[2] + acc[3]);
    }
}

// ---------------------------------------------------------------------------
// K3: residual VQ. fp32 screen (top-1 + top-2) with margin certification,
// rare exact fp64 rescan. Exact fp64 residual DISTRIBUTED (lane l<32 holds
// (m=l>>3,d=l&7)). The wave-uniform fp32 residual copy lives in SGPRs via
// per-wave LDS broadcast + readfirstlane (frees 32 VGPRs vs replicated r32
// and kills 64 serial shuffles/stream). fp32 codebook staged from the
// precomputed scratch with plain float4 copies.
// __launch_bounds__(512,3): 84-VGPR budget — 2nd arg behaves as blocks/CU
// (round-2/3 A/B: (512,4)->64 VGPR+spill, plain ->128 VGPR+2 blocks).
__global__ __launch_bounds__(512, 3) void k3_rvq(const double* __restrict__ en64,
                                                 const float2* __restrict__ en32,
                                                 const double* __restrict__ zd,
                                                 float* __restrict__ zq,
                                                 double* __restrict__ loss,
                                                 float* __restrict__ out_idx) {
    __shared__ __align__(16) float2 en_s[4 * K_];    // 32 KB: planes dp=0..3 over k
    __shared__ __align__(16) float lds_r[8 * 32];    // per-wave fp32 residual broadcast
    __shared__ double ls[8];
    int tid  = threadIdx.x;
    int wv   = tid >> 6, lane = tid & 63;
    int g     = blockIdx.x / 600;
    int chunk = blockIdx.x - g * 600;
    int mypos0 = chunk * 32 + wv * 4;
    size_t zdbase = ((size_t)g * NPOS_ + mypos0) * D_;

    const double* en64g = en64 + (size_t)g * NVQ_ * D_ * K_;
    const float2* en32g = en32 + (size_t)g * NVQ_ * 4 * K_;

    // distributed exact state: lane l<32 holds residual element (m=l>>3, d=l&7)
    double zd0 = 0.0, r64 = 0.0;
    if (lane < 32) {
        zd0 = zd[zdbase + lane];
        r64 = zd0;
        lds_r[wv * 32 + lane] = (float)r64;
    }
    double loss_acc = 0.0;

    for (int i = 0; i < NVQ_; i++) {
        __syncthreads();   // all waves done reading en_s from previous stream
        {   // stage 32 KB fp32 codebook: 2048 float4, linear copy
            const float4* src = (const float4*)(en32g + (size_t)i * 4 * K_);
            float4* dst = (float4*)en_s;
#pragma unroll
            for (int it = 0; it < 4; it++) {
                int c = it * 512 + tid;
                dst[c] = src[c];
            }
        }
        // wave-uniform fp32 residual -> SGPRs (same-wave LDS RAW, no barrier)
        float rs[4][8];
#pragma unroll
        for (int m = 0; m < 4; m++) {
            float4 f0 = *(const float4*)&lds_r[wv * 32 + m * 8];
            float4 f1 = *(const float4*)&lds_r[wv * 32 + m * 8 + 4];
            rs[m][0] = rfl(f0.x); rs[m][1] = rfl(f0.y); rs[m][2] = rfl(f0.z); rs[m][3] = rfl(f0.w);
            rs[m][4] = rfl(f1.x); rs[m][5] = rfl(f1.y); rs[m][6] = rfl(f1.z); rs[m][7] = rfl(f1.w);
        }
        __syncthreads();

        // fp32 screen: top-1 (value+index) and top-2 value per chain
        float smax[4], s2[4]; int sidx[4];
#pragma unroll
        for (int m = 0; m < 4; m++) { smax[m] = -FLT_MAX; s2[m] = -FLT_MAX; sidx[m] = 0; }
#pragma unroll 4
        for (int j = 0; j < 16; j++) {
            int k = j * 64 + lane;
            float2 c0 = en_s[k];
            float2 c1 = en_s[K_ + k];
            float2 c2 = en_s[2 * K_ + k];
            float2 c3 = en_s[3 * K_ + k];
            float cw[8] = {c0.x, c0.y, c1.x, c1.y, c2.x, c2.y, c3.x, c3.y};
#pragma unroll
            for (int m = 0; m < 4; m++) {
                float s = cw[0] * rs[m][0];
#pragma unroll
                for (int d = 1; d < 8; d++) s = fmaf(cw[d], rs[m][d], s);
                float lo = fminf(s, smax[m]);          // loser of (s, running max)
                s2[m] = fmaxf(s2[m], lo);
                if (s > smax[m]) { smax[m] = s; sidx[m] = k; }   // strict >: first index wins
            }
        }
        // cross-lane reduce (top-2 merge; first-index tie-break on top-1)
#pragma unroll
        for (int off = 32; off >= 1; off >>= 1) {
#pragma unroll
            for (int m = 0; m < 4; m++) {
                float om = __shfl_xor(smax[m], off);
                int   oi = __shfl_xor(sidx[m], off);
                float o2 = __shfl_xor(s2[m], off);
                s2[m] = fmaxf(fmaxf(s2[m], o2), fminf(smax[m], om));
                if (om > smax[m] || (om == smax[m] && oi < sidx[m])) { smax[m] = om; sidx[m] = oi; }
            }
        }
        // certify winner vs fp64; rescan exactly if the fp32 gap can't prove it.
        // |s32 - s64| <= ~10*2^-24*||r||; require gap > 4e-6*||r|| (3x margin):
        // gap^2 > 1.6e-11 * ||r||^2
#pragma unroll
        for (int m = 0; m < 4; m++) {
            float rr = 0.f;
#pragma unroll
            for (int d = 0; d < 8; d++) rr = fmaf(rs[m][d], rs[m][d], rr);
            float gap = smax[m] - s2[m];
            if (!(gap * gap > 1.6e-11f * rr)) {        // rare, wave-uniform
                double rm[8];
#pragma unroll
                for (int d = 0; d < 8; d++) rm[d] = __shfl(r64, m * 8 + d);
                const double* base = en64g + (size_t)i * D_ * K_;
                double bmax = -DBL_MAX; int bidx = 0;
                for (int j = 0; j < 16; j++) {
                    int k = j * 64 + lane;
                    double s = 0.0;
#pragma unroll
                    for (int d = 0; d < 8; d++) s = fma(base[(size_t)d * K_ + k], rm[d], s);
                    if (s > bmax) { bmax = s; bidx = k; }
                }
#pragma unroll
                for (int off = 32; off >= 1; off >>= 1) {
                    double om = __shfl_xor(bmax, off);
                    int    oi = __shfl_xor(bidx, off);
                    if (om > bmax || (om == bmax && oi < bidx)) { bmax = om; bidx = oi; }
                }
                sidx[m] = bidx;
            }
        }
        // exact distributed residual update + loss; refresh LDS broadcast copy
        int mycode = lane < 8 ? sidx[0] : lane < 16 ? sidx[1] : lane < 24 ? sidx[2] : sidx[3];
        if (lane < 32) {
            double q = en64g[((size_t)i * D_ + (lane & 7)) * K_ + mycode];
            r64 -= q;
            loss_acc = fma(r64, r64, loss_acc);
            lds_r[wv * 32 + lane] = (float)r64;
        }
        if (lane == 0) {
#pragma unroll
            for (int m = 0; m < 4; m++) {
                int pos = mypos0 + m;
                int b = pos / T_, t = pos - b * T_;
                out_idx[((size_t)(b * NVQ_ + i) * G_ + g) * T_ + t] = (float)sidx[m];
            }
        }
    }
    // zq = zd - r_final (distributed -> one element per lane, coalesced)
    if (lane < 32) zq[zdbase + lane] = (float)(zd0 - r64);
    // loss: wave tree-sum (lanes>=32 hold 0), per-block reduce, one fp64 atomic
#pragma unroll
    for (int off = 32; off >= 1; off >>= 1) loss_acc += __shfl_xor(loss_acc, off);
    if (lane == 0) ls[wv] = loss_acc;
    __syncthreads();
    if (tid == 0) {
        double s = 0.0;
#pragma unroll
        for (int w2 = 0; w2 < 8; w2++) s += ls[w2];
        atomicAdd(loss, s);
    }
}

// ---------------------------------------------------------------------------
// K4: proj_up + unfold scatter (fp32). 512 threads / 8 positions per block.
__global__ __launch_bounds__(512) void k4_up(const float* __restrict__ zq,
                                             const float* __restrict__ pu,
                                             const double* __restrict__ loss,
                                             float* __restrict__ out_zq,
                                             float* __restrict__ out_loss) {
    __shared__ __align__(16) float pu_s[G_ * GD_ * 9];   // 54 KB, row stride 9
    int tid = threadIdx.x;
#pragma unroll
    for (int it = 0; it < 3; it++) {
        int row = it * 512 + tid;            // 0..1535
        float4 lo = *(const float4*)(pu + (size_t)row * 8);
        float4 hi = *(const float4*)(pu + (size_t)row * 8 + 4);
        float* dst = &pu_s[row * 9];
        dst[0] = lo.x; dst[1] = lo.y; dst[2] = lo.z; dst[3] = lo.w;
        dst[4] = hi.x; dst[5] = hi.y; dst[6] = hi.z; dst[7] = hi.w;
    }
    if (blockIdx.x == 0 && tid == 0) {
        double l = loss[0] * (1.0 / 460800.0);   // /(B*T*D) per group, /G
        out_loss[0] = (float)l;
        out_loss[1] = (float)l;
    }
    __syncthreads();
    int wv = tid >> 6, lane = tid & 63;
    int pos = blockIdx.x * 8 + wv;
    int b = pos / T_, t = pos - b * T_;
    int ov = lane >> 4, c0 = (lane & 15) * 4;
    int gd_min = ov * FIX_ + c0 * 6;
    int g_lo = gd_min >> 9;
    int g_hi = g_lo < 2 ? g_lo + 1 : 2;
    float za[8], zb[8];
    const float* zqa = zq + ((size_t)g_lo * NPOS_ + pos) * D_;
    const float* zqb = zq + ((size_t)g_hi * NPOS_ + pos) * D_;
#pragma unroll
    for (int d = 0; d < 8; d++) { za[d] = zqa[d]; zb[d] = zqb[d]; }
#pragma unroll
    for (int h = 0; h < H_; h++) {
        float4 o;
        float* op = &o.x;
#pragma unroll
        for (int q = 0; q < 4; q++) {
            int gd = ov * FIX_ + (c0 + q) * 6 + h;
            int g  = gd >> 9;
            int j  = gd & 511;
            const float* pr = &pu_s[(g * GD_ + j) * 9];
            bool hi = (g != g_lo);
            float acc = 0.f;
#pragma unroll
            for (int d = 0; d < 8; d++) {
                float zv = hi ? zb[d] : za[d];
                acc = fmaf(zv, pr[d], acc);
            }
            op[q] = acc;
        }
        *(float4*)(out_zq + ((size_t)((b * H_ + h) * W_ + 4 * t + ov)) * C_ + c0) = o;
    }
}

// ---------------------------------------------------------------------------
extern "C" void kernel_launch(void* const* d_in, const int* in_sizes, int n_in,
                              void* d_out, int out_size, void* d_ws, size_t ws_size,
                              hipStream_t stream) {
    const float* ze = (const float*)d_in[0];
    const float* pd = (const float*)d_in[1];
    const float* pu = (const float*)d_in[2];
    const float* cb = (const float*)d_in[3];
    // d_in[4] = num_streams (==6, compile-time NVQ_)

    float* out = (float*)d_out;
    char*  ws  = (char*)d_ws;
    double* ws_en   = (double*)(ws + WS_EN);
    double* ws_zd   = (double*)(ws + WS_ZD);
    double* ws_loss = (double*)(ws + WS_LOSS);
    float*  ws_zq   = (float*)(ws + WS_ZQ);
    // fp32 codebook scratch inside the output zq region (576 KB << 118 MB),
    // fully overwritten by k4 after k3 consumes it.
    float2* en32 = (float2*)(out + OUT_ZQ);

    k1_norm_cb<<<(G_ * NVQ_ * K_ + 255) / 256, 256, 0, stream>>>(cb, ws_en, en32, ws_loss);
    k2_fold_pd<<<NPOS_ / 8, 256, 0, stream>>>(ze, pd, ws_zd);
    k3_rvq<<<G_ * (NPOS_ / 32), 512, 0, stream>>>(ws_en, en32, ws_zd, ws_zq, ws_loss, out + OUT_IDX);
    k4_up<<<NPOS_ / 8, 512, 0, stream>>>(ws_zq, pu, ws_loss, out + OUT_ZQ, out + OUT_LOSS);
}

// Round 5
// 630.061 us; speedup vs baseline: 1.1976x; 1.1541x over previous
//
#include <hip/hip_runtime.h>
#include <cfloat>
#include <math.h>

// Problem constants
constexpr int H_  = 6;
constexpr int C_  = 64;
constexpr int OV_ = 4;
constexpr int G_  = 3;
constexpr int NVQ_ = 6;
constexpr int K_  = 1024;
constexpr int D_  = 8;
constexpr int B_  = 32;
constexpr int W_  = 2400;
constexpr int T_  = 600;          // W/OV
constexpr int NPOS_ = B_ * T_;    // 19200
constexpr int FIX_ = H_ * C_;     // 384
constexpr int GD_ = 512;

// Output layout (floats, concatenated in return order)
constexpr size_t OUT_ZQ   = 0;
constexpr size_t OUT_IDX  = (size_t)B_ * H_ * W_ * C_;             // 29491200
constexpr size_t OUT_LOSS = OUT_IDX + (size_t)B_ * NVQ_ * G_ * T_; // 29836800

// Workspace layout (bytes) — IDENTICAL to the 758 µs baseline layout.
constexpr size_t WS_EN   = 0;                                   // double[18*1024*8] ROW-major [gi][k][d]
constexpr size_t WS_ZD   = WS_EN + (size_t)G_*NVQ_*K_*D_*8;     // double[3*19200*8]
constexpr size_t WS_LOSS = WS_ZD + (size_t)G_*NPOS_*D_*8;       // double[8]
constexpr size_t WS_ZQ   = WS_LOSS + 64;                        // float[3*19200*8]

// fp32 row-major codebook scratch lives in the OUTPUT buffer (first 576 KB of
// the zq region): written by k1, read by k3, fully overwritten by k4 later.

// ---------------------------------------------------------------------------
// K1: normalize codebooks (fp64); write row-major fp64 [gi][k][d] and fp32
//     [gi][k][d] copies; zero the loss accumulator.
__global__ __launch_bounds__(256) void k1_norm_cb(const float* __restrict__ cb,
                                                  double* __restrict__ en,
                                                  float* __restrict__ en32,
                                                  double* __restrict__ loss) {
    int tid = blockIdx.x * 256 + threadIdx.x;
    if (tid == 0) loss[0] = 0.0;
    if (tid >= G_ * NVQ_ * K_) return;
    int k  = tid & (K_ - 1);
    int gi = tid >> 10;               // 0..17  (g*6+i)
    const float* row = cb + ((size_t)gi * K_ + k) * D_;
    double v[D_];
    double ss = 0.0;
#pragma unroll
    for (int d = 0; d < D_; d++) { v[d] = (double)row[d]; ss += v[d] * v[d]; }
    double n = sqrt(ss);
    if (n < 1e-12) n = 1e-12;
    double* dst64 = en + ((size_t)gi * K_ + k) * D_;
    float*  dst32 = en32 + ((size_t)gi * K_ + k) * D_;
#pragma unroll
    for (int d = 0; d < D_; d++) {
        double q = v[d] / n;          // division to mimic ref
        dst64[d] = q;
        dst32[d] = (float)q;
    }
}

// ---------------------------------------------------------------------------
// K2: fold (pre_process) + proj_down, fp64 accumulation in 4 interleaved
// partials (breaks the 512-deep serial dfma chain; fixed final sum order).
constexpr int PSTR_ = 1548;
constexpr int OVS_  = 388;

__global__ __launch_bounds__(256) void k2_fold_pd(const float* __restrict__ ze,
                                                  const float* __restrict__ pd,
                                                  double* __restrict__ zd) {
    __shared__ __align__(16) float zf[8 * PSTR_];
    int tid  = threadIdx.x;
    int pos0 = blockIdx.x * 8;
#pragma unroll
    for (int it = 0; it < 12; it++) {
        int slot = it * 256 + tid;
        int seg  = slot >> 6;
        int li   = slot & 63;
        int p = seg / 6, h = seg - p * 6;
        int pos = pos0 + p;
        int b = pos / T_, t = pos - b * T_;
        const float4 vv = *(const float4*)(ze + ((size_t)((b * H_ + h) * W_ + 4 * t)) * C_ + li * 4);
        int ov = li >> 4;
        int c0 = (li & 15) * 4;
        int base = p * PSTR_ + ov * OVS_ + h;
        zf[base + (c0 + 0) * 6] = vv.x;
        zf[base + (c0 + 1) * 6] = vv.y;
        zf[base + (c0 + 2) * 6] = vv.z;
        zf[base + (c0 + 3) * 6] = vv.w;
    }
    __syncthreads();
    if (tid < 192) {
        int p = tid / 24;
        int combo = tid - p * 24;
        int g = combo >> 3, d = combo & 7;
        const float* pdp = pd + ((size_t)g * D_ + d) * GD_;
        int lbase = p * PSTR_;
        double acc[4] = {0.0, 0.0, 0.0, 0.0};
        for (int jj = 0; jj < GD_; jj += 16) {
#pragma unroll
            for (int u = 0; u < 4; u++) {
                int j4  = jj + u * 4;
                int gd  = g * GD_ + j4;
                int ov  = gd / FIX_;
                int rem = gd - ov * FIX_;
                float4 zv = *(const float4*)&zf[lbase + ov * OVS_ + rem];
                float4 pv = *(const float4*)&pdp[j4];
                acc[u] = fma((double)pv.x, (double)zv.x, acc[u]);
                acc[u] = fma((double)pv.y, (double)zv.y, acc[u]);
                acc[u] = fma((double)pv.z, (double)zv.z, acc[u]);
                acc[u] = fma((double)pv.w, (double)zv.w, acc[u]);
            }
        }
        zd[((size_t)g * NPOS_ + pos0 + p) * D_ + d] = (acc[0] + acc[1]) + (acc[2] + acc[3]);
    }
}

// ---------------------------------------------------------------------------
// K3 v2: lane-owns-chain residual VQ.
//  - 64 chains per block (one per lane), 4 waves split the 1024-codeword scan
//    4 ways (256 k each); per-lane running top-1/top-2 -> NO cross-lane
//    butterfly at all.
//  - Codewords are wave-uniform -> fetched via the SCALAR pipe (s_load from
//    L2-resident row-major fp32 codebook) into SGPRs; v_fmac reads them as
//    the scalar operand. Zero DS and zero VALU spent moving the codebook.
//  - Waves merge top-2 candidates through a tiny double-buffered LDS table
//    (one barrier per stream). All waves redundantly maintain the exact
//    per-lane fp64 residual, so no post-merge redistribution is needed.
//  - Same certification margin + rare wave-uniform fp64 rescan as before:
//    decisions are bit-identical to the fp64 scan.
__device__ __forceinline__ void screen1(const float4 lo, const float4 hi,
                                        const float r[8], int kk,
                                        float& smax, float& s2, int& sidx) {
    float s = lo.x * r[0];
    s = fmaf(lo.y, r[1], s);
    s = fmaf(lo.z, r[2], s);
    s = fmaf(lo.w, r[3], s);
    s = fmaf(hi.x, r[4], s);
    s = fmaf(hi.y, r[5], s);
    s = fmaf(hi.z, r[6], s);
    s = fmaf(hi.w, r[7], s);
    float l = fminf(s, smax);
    s2 = fmaxf(s2, l);
    if (s > smax) { smax = s; sidx = kk; }   // strict >: first index wins
}

__global__ __launch_bounds__(256) void k3_rvq(const double* __restrict__ en64,
                                              const float*  __restrict__ en32,
                                              const double* __restrict__ zd,
                                              float* __restrict__ zq,
                                              double* __restrict__ loss,
                                              float* __restrict__ out_idx) {
    __shared__ float smL[2][4][64];
    __shared__ float s2L[2][4][64];
    __shared__ int   idL[2][4][64];
    int tid  = threadIdx.x;
    int lane = tid & 63;
    int wu   = __builtin_amdgcn_readfirstlane(tid >> 6);  // wave id in SGPR ->
                                                          // uniform codebook addr
    int g     = blockIdx.x / 300;
    int chunk = blockIdx.x - g * 300;
    int pos   = chunk * 64 + lane;                        // this lane's chain
    size_t zdbase = ((size_t)g * NPOS_ + pos) * D_;

    const double* en64g = en64 + (size_t)g * NVQ_ * K_ * D_;
    const float*  en32g = en32 + (size_t)g * NVQ_ * K_ * D_;

    // exact fp64 residual, one chain per lane (replicated across the 4 waves)
    double r64[8]; float r32[8];
    {
        const double* zp = zd + zdbase;
#pragma unroll
        for (int d = 0; d < 8; d++) { r64[d] = zp[d]; r32[d] = (float)r64[d]; }
    }
    double loss_acc = 0.0;

    for (int i = 0; i < NVQ_; i++) {
        int p = i & 1;
        // ---- fp32 screen over this wave's quarter of k-space (scalar loads)
        int kb = wu * 256;
        const float* cp = en32g + ((size_t)i * K_ + kb) * D_;
        float smax = -FLT_MAX, s2 = -FLT_MAX; int sidx = 0;
        for (int c = 0; c < 256; c += 8) {
            const float4* q0 = (const float4*)(cp + (size_t)(c + 0) * 8);
            const float4* q1 = (const float4*)(cp + (size_t)(c + 1) * 8);
            const float4* q2 = (const float4*)(cp + (size_t)(c + 2) * 8);
            const float4* q3 = (const float4*)(cp + (size_t)(c + 3) * 8);
            const float4* q4 = (const float4*)(cp + (size_t)(c + 4) * 8);
            const float4* q5 = (const float4*)(cp + (size_t)(c + 5) * 8);
            const float4* q6 = (const float4*)(cp + (size_t)(c + 6) * 8);
            const float4* q7 = (const float4*)(cp + (size_t)(c + 7) * 8);
            float4 a0 = q0[0], b0 = q0[1];
            float4 a1 = q1[0], b1 = q1[1];
            float4 a2 = q2[0], b2 = q2[1];
            float4 a3 = q3[0], b3 = q3[1];
            float4 a4 = q4[0], b4 = q4[1];
            float4 a5 = q5[0], b5 = q5[1];
            float4 a6 = q6[0], b6 = q6[1];
            float4 a7 = q7[0], b7 = q7[1];
            screen1(a0, b0, r32, kb + c + 0, smax, s2, sidx);
            screen1(a1, b1, r32, kb + c + 1, smax, s2, sidx);
            screen1(a2, b2, r32, kb + c + 2, smax, s2, sidx);
            screen1(a3, b3, r32, kb + c + 3, smax, s2, sidx);
            screen1(a4, b4, r32, kb + c + 4, smax, s2, sidx);
            screen1(a5, b5, r32, kb + c + 5, smax, s2, sidx);
            screen1(a6, b6, r32, kb + c + 6, smax, s2, sidx);
            screen1(a7, b7, r32, kb + c + 7, smax, s2, sidx);
        }
        smL[p][wu][lane] = smax;
        s2L[p][wu][lane] = s2;
        idL[p][wu][lane] = sidx;
        __syncthreads();
        // ---- merge the 4 wave-candidates (all waves compute identically;
        //      w ascending = k ascending, strict > keeps smallest k)
        float sm  = smL[p][0][lane];
        float s2m = s2L[p][0][lane];
        int   si  = idL[p][0][lane];
#pragma unroll
        for (int w = 1; w < 4; w++) {
            float a  = smL[p][w][lane];
            float a2 = s2L[p][w][lane];
            int   ai = idL[p][w][lane];
            float l  = fminf(a, sm);
            s2m = fmaxf(s2m, fmaxf(l, a2));
            if (a > sm) { sm = a; si = ai; }
        }
        // ---- certify winner vs fp64; rescan exactly if gap can't prove it.
        // |s32 - s64| <= ~10*2^-24*||r||; require gap > 4e-6*||r|| (3x margin)
        float rr = 0.f;
#pragma unroll
        for (int d = 0; d < 8; d++) rr = fmaf(r32[d], r32[d], rr);
        float gap = sm - s2m;
        bool need = !(gap * gap > 1.6e-11f * rr);
        if (__any(need)) {                       // rare; wave-uniform branch
            const double* bp = en64g + (size_t)i * K_ * D_;
            double bmax = -DBL_MAX; int bidx = 0;
            for (int k = 0; k < K_; k++) {
                const double* cq = bp + (size_t)k * 8;   // uniform -> s_load
                double sA = cq[0] * r64[0];
                double sB = cq[1] * r64[1];
                sA = fma(cq[2], r64[2], sA);
                sB = fma(cq[3], r64[3], sB);
                sA = fma(cq[4], r64[4], sA);
                sB = fma(cq[5], r64[5], sB);
                sA = fma(cq[6], r64[6], sA);
                sB = fma(cq[7], r64[7], sB);
                double s = sA + sB;
                if (s > bmax) { bmax = s; bidx = k; }
            }
            if (need) si = bidx;
        }
        // ---- exact fp64 update (every wave, per lane; 64 B contiguous gather)
        {
            const double* qp = en64g + ((size_t)i * K_ + si) * D_;
            double2 q01 = *(const double2*)(qp + 0);
            double2 q23 = *(const double2*)(qp + 2);
            double2 q45 = *(const double2*)(qp + 4);
            double2 q67 = *(const double2*)(qp + 6);
            r64[0] -= q01.x; r64[1] -= q01.y;
            r64[2] -= q23.x; r64[3] -= q23.y;
            r64[4] -= q45.x; r64[5] -= q45.y;
            r64[6] -= q67.x; r64[7] -= q67.y;
#pragma unroll
            for (int d = 0; d < 8; d++) r32[d] = (float)r64[d];
        }
        if (wu == 0) {
#pragma unroll
            for (int d = 0; d < 8; d++) loss_acc = fma(r64[d], r64[d], loss_acc);
            int b = pos / T_, t = pos - b * T_;
            out_idx[((size_t)(b * NVQ_ + i) * G_ + g) * T_ + t] = (float)si;
        }
    }
    // ---- epilogue: wave 0 writes zq and reduces loss
    if (wu == 0) {
        const double* zp = zd + zdbase;
        float4 o0, o1;
        o0.x = (float)(zp[0] - r64[0]);
        o0.y = (float)(zp[1] - r64[1]);
        o0.z = (float)(zp[2] - r64[2]);
        o0.w = (float)(zp[3] - r64[3]);
        o1.x = (float)(zp[4] - r64[4]);
        o1.y = (float)(zp[5] - r64[5]);
        o1.z = (float)(zp[6] - r64[6]);
        o1.w = (float)(zp[7] - r64[7]);
        *(float4*)(zq + zdbase)     = o0;
        *(float4*)(zq + zdbase + 4) = o1;
#pragma unroll
        for (int off = 32; off >= 1; off >>= 1) loss_acc += __shfl_xor(loss_acc, off);
        if (lane == 0) atomicAdd(loss, loss_acc);
    }
}

// ---------------------------------------------------------------------------
// K4: proj_up + unfold scatter (fp32). 512 threads / 8 positions per block.
__global__ __launch_bounds__(512) void k4_up(const float* __restrict__ zq,
                                             const float* __restrict__ pu,
                                             const double* __restrict__ loss,
                                             float* __restrict__ out_zq,
                                             float* __restrict__ out_loss) {
    __shared__ __align__(16) float pu_s[G_ * GD_ * 9];   // 54 KB, row stride 9
    int tid = threadIdx.x;
#pragma unroll
    for (int it = 0; it < 3; it++) {
        int row = it * 512 + tid;            // 0..1535
        float4 lo = *(const float4*)(pu + (size_t)row * 8);
        float4 hi = *(const float4*)(pu + (size_t)row * 8 + 4);
        float* dst = &pu_s[row * 9];
        dst[0] = lo.x; dst[1] = lo.y; dst[2] = lo.z; dst[3] = lo.w;
        dst[4] = hi.x; dst[5] = hi.y; dst[6] = hi.z; dst[7] = hi.w;
    }
    if (blockIdx.x == 0 && tid == 0) {
        double l = loss[0] * (1.0 / 460800.0);   // /(B*T*D) per group, /G
        out_loss[0] = (float)l;
        out_loss[1] = (float)l;
    }
    __syncthreads();
    int wv = tid >> 6, lane = tid & 63;
    int pos = blockIdx.x * 8 + wv;
    int b = pos / T_, t = pos - b * T_;
    int ov = lane >> 4, c0 = (lane & 15) * 4;
    int gd_min = ov * FIX_ + c0 * 6;
    int g_lo = gd_min >> 9;
    int g_hi = g_lo < 2 ? g_lo + 1 : 2;
    float za[8], zb[8];
    const float* zqa = zq + ((size_t)g_lo * NPOS_ + pos) * D_;
    const float* zqb = zq + ((size_t)g_hi * NPOS_ + pos) * D_;
#pragma unroll
    for (int d = 0; d < 8; d++) { za[d] = zqa[d]; zb[d] = zqb[d]; }
#pragma unroll
    for (int h = 0; h < H_; h++) {
        float4 o;
        float* op = &o.x;
#pragma unroll
        for (int q = 0; q < 4; q++) {
            int gd = ov * FIX_ + (c0 + q) * 6 + h;
            int g  = gd >> 9;
            int j  = gd & 511;
            const float* pr = &pu_s[(g * GD_ + j) * 9];
            bool hi = (g != g_lo);
            float acc = 0.f;
#pragma unroll
            for (int d = 0; d < 8; d++) {
                float zv = hi ? zb[d] : za[d];
                acc = fmaf(zv, pr[d], acc);
            }
            op[q] = acc;
        }
        *(float4*)(out_zq + ((size_t)((b * H_ + h) * W_ + 4 * t + ov)) * C_ + c0) = o;
    }
}

// ---------------------------------------------------------------------------
extern "C" void kernel_launch(void* const* d_in, const int* in_sizes, int n_in,
                              void* d_out, int out_size, void* d_ws, size_t ws_size,
                              hipStream_t stream) {
    const float* ze = (const float*)d_in[0];
    const float* pd = (const float*)d_in[1];
    const float* pu = (const float*)d_in[2];
    const float* cb = (const float*)d_in[3];
    // d_in[4] = num_streams (==6, compile-time NVQ_)

    float* out = (float*)d_out;
    char*  ws  = (char*)d_ws;
    double* ws_en   = (double*)(ws + WS_EN);
    double* ws_zd   = (double*)(ws + WS_ZD);
    double* ws_loss = (double*)(ws + WS_LOSS);
    float*  ws_zq   = (float*)(ws + WS_ZQ);
    // fp32 row-major codebook scratch inside the output zq region (576 KB),
    // fully overwritten by k4 after k3 consumes it.
    float* en32 = out + OUT_ZQ;

    k1_norm_cb<<<(G_ * NVQ_ * K_ + 255) / 256, 256, 0, stream>>>(cb, ws_en, en32, ws_loss);
    k2_fold_pd<<<NPOS_ / 8, 256, 0, stream>>>(ze, pd, ws_zd);
    k3_rvq<<<G_ * (NPOS_ / 64), 256, 0, stream>>>(ws_en, en32, ws_zd, ws_zq, ws_loss, out + OUT_IDX);
    k4_up<<<NPOS_ / 8, 512, 0, stream>>>(ws_zq, pu, ws_loss, out + OUT_ZQ, out + OUT_LOSS);
}

// Round 6
// 581.081 us; speedup vs baseline: 1.2986x; 1.0843x over previous
//
#include <hip/hip_runtime.h>
#include <cfloat>
#include <math.h>

// Problem constants
constexpr int H_  = 6;
constexpr int C_  = 64;
constexpr int OV_ = 4;
constexpr int G_  = 3;
constexpr int NVQ_ = 6;
constexpr int K_  = 1024;
constexpr int D_  = 8;
constexpr int B_  = 32;
constexpr int W_  = 2400;
constexpr int T_  = 600;          // W/OV
constexpr int NPOS_ = B_ * T_;    // 19200
constexpr int FIX_ = H_ * C_;     // 384
constexpr int GD_ = 512;

// Output layout (floats, concatenated in return order)
constexpr size_t OUT_ZQ   = 0;
constexpr size_t OUT_IDX  = (size_t)B_ * H_ * W_ * C_;             // 29491200
constexpr size_t OUT_LOSS = OUT_IDX + (size_t)B_ * NVQ_ * G_ * T_; // 29836800

// Workspace layout (bytes) — IDENTICAL to the 758 µs baseline layout.
constexpr size_t WS_EN   = 0;                                   // double[18*1024*8] ROW-major [gi][k][d]
constexpr size_t WS_ZD   = WS_EN + (size_t)G_*NVQ_*K_*D_*8;     // double[3*19200*8]
constexpr size_t WS_LOSS = WS_ZD + (size_t)G_*NPOS_*D_*8;       // double[8]
constexpr size_t WS_ZQ   = WS_LOSS + 64;                        // float[3*19200*8]

// fp32 row-major codebook scratch lives in the OUTPUT buffer (first 576 KB of
// the zq region): written by k1, read by k3, fully overwritten by k4 later.

// ---------------------------------------------------------------------------
// K1: normalize codebooks (fp64); write row-major fp64 [gi][k][d] and fp32
//     [gi][k][d] copies; zero the loss accumulator.
__global__ __launch_bounds__(256) void k1_norm_cb(const float* __restrict__ cb,
                                                  double* __restrict__ en,
                                                  float* __restrict__ en32,
                                                  double* __restrict__ loss) {
    int tid = blockIdx.x * 256 + threadIdx.x;
    if (tid == 0) loss[0] = 0.0;
    if (tid >= G_ * NVQ_ * K_) return;
    int k  = tid & (K_ - 1);
    int gi = tid >> 10;               // 0..17  (g*6+i)
    const float* row = cb + ((size_t)gi * K_ + k) * D_;
    double v[D_];
    double ss = 0.0;
#pragma unroll
    for (int d = 0; d < D_; d++) { v[d] = (double)row[d]; ss += v[d] * v[d]; }
    double n = sqrt(ss);
    if (n < 1e-12) n = 1e-12;
    double* dst64 = en + ((size_t)gi * K_ + k) * D_;
    float*  dst32 = en32 + ((size_t)gi * K_ + k) * D_;
#pragma unroll
    for (int d = 0; d < D_; d++) {
        double q = v[d] / n;          // division to mimic ref
        dst64[d] = q;
        dst32[d] = (float)q;
    }
}

// ---------------------------------------------------------------------------
// K2: fold (pre_process) + proj_down, fp64 accumulation in 4 interleaved
// partials (breaks the 512-deep serial dfma chain; fixed final sum order).
constexpr int PSTR_ = 1548;
constexpr int OVS_  = 388;

__global__ __launch_bounds__(256) void k2_fold_pd(const float* __restrict__ ze,
                                                  const float* __restrict__ pd,
                                                  double* __restrict__ zd) {
    __shared__ __align__(16) float zf[8 * PSTR_];
    int tid  = threadIdx.x;
    int pos0 = blockIdx.x * 8;
#pragma unroll
    for (int it = 0; it < 12; it++) {
        int slot = it * 256 + tid;
        int seg  = slot >> 6;
        int li   = slot & 63;
        int p = seg / 6, h = seg - p * 6;
        int pos = pos0 + p;
        int b = pos / T_, t = pos - b * T_;
        const float4 vv = *(const float4*)(ze + ((size_t)((b * H_ + h) * W_ + 4 * t)) * C_ + li * 4);
        int ov = li >> 4;
        int c0 = (li & 15) * 4;
        int base = p * PSTR_ + ov * OVS_ + h;
        zf[base + (c0 + 0) * 6] = vv.x;
        zf[base + (c0 + 1) * 6] = vv.y;
        zf[base + (c0 + 2) * 6] = vv.z;
        zf[base + (c0 + 3) * 6] = vv.w;
    }
    __syncthreads();
    if (tid < 192) {
        int p = tid / 24;
        int combo = tid - p * 24;
        int g = combo >> 3, d = combo & 7;
        const float* pdp = pd + ((size_t)g * D_ + d) * GD_;
        int lbase = p * PSTR_;
        double acc[4] = {0.0, 0.0, 0.0, 0.0};
        for (int jj = 0; jj < GD_; jj += 16) {
#pragma unroll
            for (int u = 0; u < 4; u++) {
                int j4  = jj + u * 4;
                int gd  = g * GD_ + j4;
                int ov  = gd / FIX_;
                int rem = gd - ov * FIX_;
                float4 zv = *(const float4*)&zf[lbase + ov * OVS_ + rem];
                float4 pv = *(const float4*)&pdp[j4];
                acc[u] = fma((double)pv.x, (double)zv.x, acc[u]);
                acc[u] = fma((double)pv.y, (double)zv.y, acc[u]);
                acc[u] = fma((double)pv.z, (double)zv.z, acc[u]);
                acc[u] = fma((double)pv.w, (double)zv.w, acc[u]);
            }
        }
        zd[((size_t)g * NPOS_ + pos0 + p) * D_ + d] = (acc[0] + acc[1]) + (acc[2] + acc[3]);
    }
}

// ---------------------------------------------------------------------------
// K3 v3: lane-owns-chain residual VQ — now 8 waves/block (512 threads), each
// wave scans 128 codewords (k = wu*128 .. +127) via scalar-pipe loads.
// Round-5 showed the 4-wave version was grid-starved (3.5 waves/SIMD,
// Occupancy 25%): same total VALU, 2x the waves -> ~28 waves/CU.
// (512,4): 64-VGPR budget, kernel lives in ~35 -> no spill (round-2 lesson).
__device__ __forceinline__ void screen1(const float4 lo, const float4 hi,
                                        const float r[8], int kk,
                                        float& smax, float& s2, int& sidx) {
    float s = lo.x * r[0];
    s = fmaf(lo.y, r[1], s);
    s = fmaf(lo.z, r[2], s);
    s = fmaf(lo.w, r[3], s);
    s = fmaf(hi.x, r[4], s);
    s = fmaf(hi.y, r[5], s);
    s = fmaf(hi.z, r[6], s);
    s = fmaf(hi.w, r[7], s);
    float l = fminf(s, smax);
    s2 = fmaxf(s2, l);
    if (s > smax) { smax = s; sidx = kk; }   // strict >: first index wins
}

__global__ __launch_bounds__(512, 4) void k3_rvq(const double* __restrict__ en64,
                                                 const float*  __restrict__ en32,
                                                 const double* __restrict__ zd,
                                                 float* __restrict__ zq,
                                                 double* __restrict__ loss,
                                                 float* __restrict__ out_idx) {
    __shared__ float smL[2][8][64];
    __shared__ float s2L[2][8][64];
    __shared__ int   idL[2][8][64];
    int tid  = threadIdx.x;
    int lane = tid & 63;
    int wu   = __builtin_amdgcn_readfirstlane(tid >> 6);  // wave id in SGPR ->
                                                          // uniform codebook addr
    int g     = blockIdx.x / 300;
    int chunk = blockIdx.x - g * 300;
    int pos   = chunk * 64 + lane;                        // this lane's chain
    size_t zdbase = ((size_t)g * NPOS_ + pos) * D_;

    const double* en64g = en64 + (size_t)g * NVQ_ * K_ * D_;
    const float*  en32g = en32 + (size_t)g * NVQ_ * K_ * D_;

    // exact fp64 residual, one chain per lane (replicated across the 8 waves)
    double r64[8]; float r32[8];
    {
        const double* zp = zd + zdbase;
#pragma unroll
        for (int d = 0; d < 8; d++) { r64[d] = zp[d]; r32[d] = (float)r64[d]; }
    }
    double loss_acc = 0.0;

    for (int i = 0; i < NVQ_; i++) {
        int p = i & 1;
        // ---- fp32 screen over this wave's eighth of k-space (scalar loads)
        int kb = wu * 128;
        const float* cp = en32g + ((size_t)i * K_ + kb) * D_;
        float smax = -FLT_MAX, s2 = -FLT_MAX; int sidx = 0;
        for (int c = 0; c < 128; c += 8) {
            const float4* q0 = (const float4*)(cp + (size_t)(c + 0) * 8);
            const float4* q1 = (const float4*)(cp + (size_t)(c + 1) * 8);
            const float4* q2 = (const float4*)(cp + (size_t)(c + 2) * 8);
            const float4* q3 = (const float4*)(cp + (size_t)(c + 3) * 8);
            const float4* q4 = (const float4*)(cp + (size_t)(c + 4) * 8);
            const float4* q5 = (const float4*)(cp + (size_t)(c + 5) * 8);
            const float4* q6 = (const float4*)(cp + (size_t)(c + 6) * 8);
            const float4* q7 = (const float4*)(cp + (size_t)(c + 7) * 8);
            float4 a0 = q0[0], b0 = q0[1];
            float4 a1 = q1[0], b1 = q1[1];
            float4 a2 = q2[0], b2 = q2[1];
            float4 a3 = q3[0], b3 = q3[1];
            float4 a4 = q4[0], b4 = q4[1];
            float4 a5 = q5[0], b5 = q5[1];
            float4 a6 = q6[0], b6 = q6[1];
            float4 a7 = q7[0], b7 = q7[1];
            screen1(a0, b0, r32, kb + c + 0, smax, s2, sidx);
            screen1(a1, b1, r32, kb + c + 1, smax, s2, sidx);
            screen1(a2, b2, r32, kb + c + 2, smax, s2, sidx);
            screen1(a3, b3, r32, kb + c + 3, smax, s2, sidx);
            screen1(a4, b4, r32, kb + c + 4, smax, s2, sidx);
            screen1(a5, b5, r32, kb + c + 5, smax, s2, sidx);
            screen1(a6, b6, r32, kb + c + 6, smax, s2, sidx);
            screen1(a7, b7, r32, kb + c + 7, smax, s2, sidx);
        }
        smL[p][wu][lane] = smax;
        s2L[p][wu][lane] = s2;
        idL[p][wu][lane] = sidx;
        __syncthreads();
        // ---- merge the 8 wave-candidates (all waves compute identically;
        //      w ascending = k ascending, strict > keeps smallest k)
        float sm  = smL[p][0][lane];
        float s2m = s2L[p][0][lane];
        int   si  = idL[p][0][lane];
#pragma unroll
        for (int w = 1; w < 8; w++) {
            float a  = smL[p][w][lane];
            float a2 = s2L[p][w][lane];
            int   ai = idL[p][w][lane];
            float l  = fminf(a, sm);
            s2m = fmaxf(s2m, fmaxf(l, a2));
            if (a > sm) { sm = a; si = ai; }
        }
        // ---- certify winner vs fp64; rescan exactly if gap can't prove it.
        // |s32 - s64| <= ~10*2^-24*||r||; require gap > 4e-6*||r|| (3x margin)
        float rr = 0.f;
#pragma unroll
        for (int d = 0; d < 8; d++) rr = fmaf(r32[d], r32[d], rr);
        float gap = sm - s2m;
        bool need = !(gap * gap > 1.6e-11f * rr);
        if (__any(need)) {                       // rare; wave-uniform branch
            const double* bp = en64g + (size_t)i * K_ * D_;
            double bmax = -DBL_MAX; int bidx = 0;
            for (int k = 0; k < K_; k++) {
                const double* cq = bp + (size_t)k * 8;   // uniform -> s_load
                double sA = cq[0] * r64[0];
                double sB = cq[1] * r64[1];
                sA = fma(cq[2], r64[2], sA);
                sB = fma(cq[3], r64[3], sB);
                sA = fma(cq[4], r64[4], sA);
                sB = fma(cq[5], r64[5], sB);
                sA = fma(cq[6], r64[6], sA);
                sB = fma(cq[7], r64[7], sB);
                double s = sA + sB;
                if (s > bmax) { bmax = s; bidx = k; }
            }
            if (need) si = bidx;
        }
        // ---- exact fp64 update (every wave, per lane; 64 B contiguous gather)
        {
            const double* qp = en64g + ((size_t)i * K_ + si) * D_;
            double2 q01 = *(const double2*)(qp + 0);
            double2 q23 = *(const double2*)(qp + 2);
            double2 q45 = *(const double2*)(qp + 4);
            double2 q67 = *(const double2*)(qp + 6);
            r64[0] -= q01.x; r64[1] -= q01.y;
            r64[2] -= q23.x; r64[3] -= q23.y;
            r64[4] -= q45.x; r64[5] -= q45.y;
            r64[6] -= q67.x; r64[7] -= q67.y;
#pragma unroll
            for (int d = 0; d < 8; d++) r32[d] = (float)r64[d];
        }
        if (wu == 0) {
#pragma unroll
            for (int d = 0; d < 8; d++) loss_acc = fma(r64[d], r64[d], loss_acc);
            int b = pos / T_, t = pos - b * T_;
            out_idx[((size_t)(b * NVQ_ + i) * G_ + g) * T_ + t] = (float)si;
        }
    }
    // ---- epilogue: wave 0 writes zq and reduces loss
    if (wu == 0) {
        const double* zp = zd + zdbase;
        float4 o0, o1;
        o0.x = (float)(zp[0] - r64[0]);
        o0.y = (float)(zp[1] - r64[1]);
        o0.z = (float)(zp[2] - r64[2]);
        o0.w = (float)(zp[3] - r64[3]);
        o1.x = (float)(zp[4] - r64[4]);
        o1.y = (float)(zp[5] - r64[5]);
        o1.z = (float)(zp[6] - r64[6]);
        o1.w = (float)(zp[7] - r64[7]);
        *(float4*)(zq + zdbase)     = o0;
        *(float4*)(zq + zdbase + 4) = o1;
#pragma unroll
        for (int off = 32; off >= 1; off >>= 1) loss_acc += __shfl_xor(loss_acc, off);
        if (lane == 0) atomicAdd(loss, loss_acc);
    }
}

// ---------------------------------------------------------------------------
// K4: proj_up + unfold scatter (fp32). pu_s now NATURAL stride-8 rows (16B
// aligned -> ds_read_b128) with XOR swizzle byte^=((byte>>8)&7)<<4 (bijective
// involution; control bits above flipped bits). Lane row index == gd; gd%4 is
// lane-invariant (the old 16-way trap) but (gd>>3)&7 cycles all 8 chunk slots
// across c0-lanes -> reads spread over all 32 banks. 192 conflicted scalar
// reads/thread -> 48 clean b128 reads.
__device__ __forceinline__ int swz48(int byte) {
    return byte ^ (((byte >> 8) & 7) << 4);
}

__global__ __launch_bounds__(512) void k4_up(const float* __restrict__ zq,
                                             const float* __restrict__ pu,
                                             const double* __restrict__ loss,
                                             float* __restrict__ out_zq,
                                             float* __restrict__ out_loss) {
    __shared__ __align__(16) float pu_s[G_ * GD_ * 8];   // 48 KB, swizzled
    char* pb = (char*)pu_s;
    int tid = threadIdx.x;
#pragma unroll
    for (int it = 0; it < 3; it++) {
        int row = it * 512 + tid;            // 0..1535
        float4 lo = *(const float4*)(pu + (size_t)row * 8);
        float4 hi = *(const float4*)(pu + (size_t)row * 8 + 4);
        int byte0 = row * 32;
        *(float4*)(pb + swz48(byte0))      = lo;
        *(float4*)(pb + swz48(byte0 + 16)) = hi;
    }
    if (blockIdx.x == 0 && tid == 0) {
        double l = loss[0] * (1.0 / 460800.0);   // /(B*T*D) per group, /G
        out_loss[0] = (float)l;
        out_loss[1] = (float)l;
    }
    __syncthreads();
    int wv = tid >> 6, lane = tid & 63;
    int pos = blockIdx.x * 8 + wv;
    int b = pos / T_, t = pos - b * T_;
    int ov = lane >> 4, c0 = (lane & 15) * 4;
    int gd_min = ov * FIX_ + c0 * 6;
    int g_lo = gd_min >> 9;
    int g_hi = g_lo < 2 ? g_lo + 1 : 2;
    float za[8], zb[8];
    const float* zqa = zq + ((size_t)g_lo * NPOS_ + pos) * D_;
    const float* zqb = zq + ((size_t)g_hi * NPOS_ + pos) * D_;
#pragma unroll
    for (int d = 0; d < 8; d++) { za[d] = zqa[d]; zb[d] = zqb[d]; }
#pragma unroll
    for (int h = 0; h < H_; h++) {
        float4 o;
        float* op = &o.x;
#pragma unroll
        for (int q = 0; q < 4; q++) {
            int gd = ov * FIX_ + (c0 + q) * 6 + h;   // == row in pu_s
            int byte0 = gd * 32;
            float4 fa = *(const float4*)(pb + swz48(byte0));
            float4 fb = *(const float4*)(pb + swz48(byte0 + 16));
            bool hi = ((gd >> 9) != g_lo);
            const float* zv = hi ? zb : za;
            float acc = zv[0] * fa.x;
            acc = fmaf(zv[1], fa.y, acc);
            acc = fmaf(zv[2], fa.z, acc);
            acc = fmaf(zv[3], fa.w, acc);
            acc = fmaf(zv[4], fb.x, acc);
            acc = fmaf(zv[5], fb.y, acc);
            acc = fmaf(zv[6], fb.z, acc);
            acc = fmaf(zv[7], fb.w, acc);
            op[q] = acc;
        }
        *(float4*)(out_zq + ((size_t)((b * H_ + h) * W_ + 4 * t + ov)) * C_ + c0) = o;
    }
}

// ---------------------------------------------------------------------------
extern "C" void kernel_launch(void* const* d_in, const int* in_sizes, int n_in,
                              void* d_out, int out_size, void* d_ws, size_t ws_size,
                              hipStream_t stream) {
    const float* ze = (const float*)d_in[0];
    const float* pd = (const float*)d_in[1];
    const float* pu = (const float*)d_in[2];
    const float* cb = (const float*)d_in[3];
    // d_in[4] = num_streams (==6, compile-time NVQ_)

    float* out = (float*)d_out;
    char*  ws  = (char*)d_ws;
    double* ws_en   = (double*)(ws + WS_EN);
    double* ws_zd   = (double*)(ws + WS_ZD);
    double* ws_loss = (double*)(ws + WS_LOSS);
    float*  ws_zq   = (float*)(ws + WS_ZQ);
    // fp32 row-major codebook scratch inside the output zq region (576 KB),
    // fully overwritten by k4 after k3 consumes it.
    float* en32 = out + OUT_ZQ;

    k1_norm_cb<<<(G_ * NVQ_ * K_ + 255) / 256, 256, 0, stream>>>(cb, ws_en, en32, ws_loss);
    k2_fold_pd<<<NPOS_ / 8, 256, 0, stream>>>(ze, pd, ws_zd);
    k3_rvq<<<G_ * (NPOS_ / 64), 512, 0, stream>>>(ws_en, en32, ws_zd, ws_zq, ws_loss, out + OUT_IDX);
    k4_up<<<NPOS_ / 8, 512, 0, stream>>>(ws_zq, pu, ws_loss, out + OUT_ZQ, out + OUT_LOSS);
}